// Round 6
// baseline (1827.659 us; speedup 1.0000x reference)
//
#include <hip/hip_runtime.h>
#include <math.h>

// N=511 complete binary tree: nodes 0..254 internal, 255..510 leaves.
// B=128, M=256, IN=512, R=64.
// Gate-interleaved bf16 weight layouts fuse every LSTM-cell epilogue into its
// producing GEMM. Staging via global_load_lds width=16; unpadded LDS tiles
// with XOR k-slot swizzle compensated in the per-lane global source address.
// R5: fast exp2/rcp transcendentals + XCD block remap. R6/7: dbuf +
// counted-vmcnt K-loop (helped leaf/g1/g2; null on g3). R8: epilogue operand
// prefetch. R9: PR eliminated via [h1|AinR] K-extension in gemm2.
// R10 (this): (a) k_tail -- levels 4..0 fused into ONE kernel with a
// device-scope grid barrier (was 15 latency-bound launches ~130-150 us);
// (b) k_leaf multi-row-tile blocks (RT=4): next tile's k=0 stage issues
// during the previous tile's last step, epilogue hides prologue latency.
#define NNODE 511

typedef short s16x8 __attribute__((ext_vector_type(8)));
typedef float f32x4 __attribute__((ext_vector_type(4)));

__device__ __forceinline__ unsigned short f2bf(float f) {
  unsigned int u = __builtin_bit_cast(unsigned int, f);
  u += 0x7fffu + ((u >> 16) & 1u);           // RNE
  return (unsigned short)(u >> 16);
}
__device__ __forceinline__ float sigf(float x) {
  float e = __builtin_amdgcn_exp2f(-1.442695040888963f * x);
  return __builtin_amdgcn_rcpf(1.0f + e);
}
__device__ __forceinline__ float tanh_a(float x) {
  float e = __builtin_amdgcn_exp2f(2.885390081777927f * x);
  return 1.0f - 2.0f * __builtin_amdgcn_rcpf(1.0f + e);
}

__device__ __forceinline__ void load16_lds(const unsigned short* g, unsigned short* l) {
  __builtin_amdgcn_global_load_lds(
      (const __attribute__((address_space(1))) void*)g,
      (__attribute__((address_space(3))) void*)l, 16, 0, 0);
}

template<int N> __device__ __forceinline__ void s_wait_vmcnt() {
  asm volatile("s_waitcnt vmcnt(%0)" :: "n"(N) : "memory");
}

// XCD-aware block remap (bijective when ny%8==0; tail launches L2-fit).
__device__ __forceinline__ void swz_blk(int& bx, int& by) {
  bx = blockIdx.x; by = blockIdx.y;
  int ny = gridDim.y;
  if ((ny & 7) == 0) {
    int lin = by * 8 + bx;
    int w = lin >> 3;
    by = (lin & 7) * (ny >> 3) + (w >> 3);
    bx = w & 7;
  }
}

// Device-scope grid barrier (sense via generation counter). Writer side:
// __syncthreads drains all waves' stores (vmcnt0), thread0's fence+release
// RMW write-backs the XCD L2. Reader side: acquire loads invalidate L1/L2.
__device__ __forceinline__ void gridbar(unsigned* cnt, unsigned* gen) {
  __syncthreads();
  if (threadIdx.x == 0) {
    __threadfence();
    unsigned nb = gridDim.x * gridDim.y;
    unsigned g = __hip_atomic_load(gen, __ATOMIC_RELAXED, __HIP_MEMORY_SCOPE_AGENT);
    unsigned a = __hip_atomic_fetch_add(cnt, 1u, __ATOMIC_ACQ_REL, __HIP_MEMORY_SCOPE_AGENT);
    if (a == nb - 1u) {
      __hip_atomic_store(cnt, 0u, __ATOMIC_RELAXED, __HIP_MEMORY_SCOPE_AGENT);
      __hip_atomic_fetch_add(gen, 1u, __ATOMIC_RELEASE, __HIP_MEMORY_SCOPE_AGENT);
    } else {
      while (__hip_atomic_load(gen, __ATOMIC_ACQUIRE, __HIP_MEMORY_SCOPE_AGENT) == g) {
        __builtin_amdgcn_s_sleep(2);
      }
    }
  }
  __syncthreads();
}

// ---------------------------------------------------------------------------
// wte (B,511,512) fp32 -> xbf (node,b,k) bf16, node-major. Also zeroes the
// grid-barrier counters (workspace is re-poisoned every iteration).
__global__ void k_prep_x(const float* __restrict__ w, unsigned short* __restrict__ xbf,
                         unsigned* __restrict__ bar) {
  if (blockIdx.x == 0 && threadIdx.x == 0) { bar[0] = 0u; bar[1] = 0u; }
  int o = (blockIdx.x * 256 + threadIdx.x) * 4;
  int node = o >> 16;
  int b = (o >> 9) & 127;
  int k = o & 511;
  const float4 v = *(const float4*)(w + ((size_t)b * NNODE + node) * 512 + k);
  unsigned int p0 = (unsigned int)f2bf(v.x) | ((unsigned int)f2bf(v.y) << 16);
  unsigned int p1 = (unsigned int)f2bf(v.z) | ((unsigned int)f2bf(v.w) << 16);
  *(uint2*)(xbf + o) = make_uint2(p0, p1);
}

// ---------------------------------------------------------------------------
// Gate-interleaved transposed weights:
//  WL2t (768,512):  c = 48G+16g+mi, g in {i,u,o}
//  WA2t (1280,320): c = 80G+16g+mi, g in {i,f,g,o,fh}
//  WG2t (1280,576): c = 80G+16g+mi; g<4: k<256 Wsh, k>=256 Wsi; g==4 Wfh on 256..511
//  WEX2t(1024,768): c = 64G+16g+mi, g in {i,u,o,f}; k<256 h-w, k>=256 x-w
__global__ void k_prep_w(const float* __restrict__ Wix, const float* __restrict__ Wux,
                         const float* __restrict__ Wox, const float* __restrict__ Wfx,
                         const float* __restrict__ Wih, const float* __restrict__ Wuh,
                         const float* __restrict__ Woh, const float* __restrict__ Wfh,
                         const float* __restrict__ Wsi, const float* __restrict__ Wsh,
                         unsigned short* __restrict__ WL2t, unsigned short* __restrict__ WA2t,
                         unsigned short* __restrict__ WG2t, unsigned short* __restrict__ WEX2t) {
  int idx = blockIdx.x * 256 + threadIdx.x;
  if (idx < 393216) {                       // WL2t 768*512
    int c = idx >> 9, k = idx & 511;
    int G = c / 48, rem = c - G * 48, g = rem >> 4, mi = rem & 15, m = G * 16 + mi;
    const float* W = (g == 0) ? Wix : (g == 1) ? Wux : Wox;
    WL2t[idx] = f2bf(W[k * 256 + m]);
  } else if (idx < 802816) {                // WA2t 1280*320
    int o = idx - 393216;
    int c = o / 320, k = o - c * 320;
    int G = c / 80, rem = c - G * 80, g = rem >> 4, mi = rem & 15, m = G * 16 + mi;
    float v;
    if (g < 4) v = Wsi[k * 1024 + g * 256 + m];
    else       v = (k < 256) ? Wfh[k * 256 + m] : 0.0f;
    WA2t[o] = f2bf(v);
  } else if (idx < 1540096) {               // WG2t 1280*576
    int o = idx - 802816;
    int c = o / 576, k = o - c * 576;
    int G = c / 80, rem = c - G * 80, g = rem >> 4, mi = rem & 15, m = G * 16 + mi;
    float v;
    if (g < 4) v = (k < 256) ? Wsh[k * 1024 + g * 256 + m]
                             : Wsi[(k - 256) * 1024 + g * 256 + m];
    else       v = (k >= 256 && k < 512) ? Wfh[(k - 256) * 256 + m] : 0.0f;
    WG2t[o] = f2bf(v);
  } else if (idx < 2326528) {               // WEX2t 1024*768
    int o = idx - 1540096;
    int c = o / 768, k = o - c * 768;
    int G = c >> 6, rem = c & 63, g = rem >> 4, mi = rem & 15, m = G * 16 + mi;
    float v;
    if (k < 256) {
      v = (g == 0) ? Wih[k * 256 + m] : (g == 1) ? Wuh[k * 256 + m]
        : (g == 2) ? Woh[k * 256 + m] : 0.0f;
    } else {
      int k2 = k - 256;
      v = (g == 0) ? Wix[k2 * 256 + m] : (g == 1) ? Wux[k2 * 256 + m]
        : (g == 2) ? Wox[k2 * 256 + m] : Wfx[k2 * 256 + m];
    }
    WEX2t[o] = f2bf(v);
  }
}

// Swizzled MFMA inner step. sw(kk) = (kk | q*8) ^ ((m16&7)*8).
#define MFMA_BODY(AP, BP, NG, CW)                                             \
  _Pragma("unroll")                                                           \
  for (int kk = 0; kk < 64; kk += 32) {                                       \
    const int sw = (kk | (q * 8)) ^ ((m16 & 7) * 8);                          \
    s16x8 af[4], bfr[NG];                                                     \
    _Pragma("unroll")                                                         \
    for (int i = 0; i < 4; ++i)                                               \
      af[i] = *(const s16x8*)(&(AP)[(wm + i * 16 + m16) * 64 + sw]);          \
    _Pragma("unroll")                                                         \
    for (int j = 0; j < NG; ++j)                                              \
      bfr[j] = *(const s16x8*)(&(BP)[(wc * CW + j * 16 + m16) * 64 + sw]);    \
    _Pragma("unroll")                                                         \
    for (int i = 0; i < 4; ++i)                                               \
      _Pragma("unroll")                                                       \
      for (int j = 0; j < NG; ++j)                                            \
        acc[i][j] = __builtin_amdgcn_mfma_f32_16x16x32_bf16(af[i], bfr[j], acc[i][j], 0, 0, 0); \
  }

#define STAGE(DST, SRC, STRIDE, R, K0)                                        \
  _Pragma("unroll")                                                           \
  for (int c = 0; c < (R) / 32; ++c) {                                        \
    int row8 = wave * ((R) / 4) + c * 8;                                      \
    load16_lds(SRC + (size_t)(row8 + l8) * (STRIDE) + (K0) + gsw, &(DST)[row8 * 64]); \
  }

#define STEP_SYNC(VM)                                                         \
  s_wait_vmcnt<VM>();                                                         \
  __builtin_amdgcn_s_barrier();                                               \
  __builtin_amdgcn_sched_barrier(0);

#define LANE_SETUP                                                            \
  const int t = threadIdx.x;                                                  \
  const int wave = t >> 6, lane = t & 63;                                     \
  const int wm = (wave & 1) * 64, wc = wave >> 1;                             \
  const int m16 = lane & 15, q = lane >> 4;                                   \
  const int l8 = lane >> 3, l7 = lane & 7;                                    \
  const int gsw = ((l7 ^ l8) * 8);

// ---------------------------------------------------------------------------
// GEMM1 + cell1 epilogue. A = AinL (crows x 320 bf16), B = WA2t.
__global__ __launch_bounds__(256, 2) void k_gemm1(
    const unsigned short* __restrict__ AinL, const unsigned short* __restrict__ Bt,
    unsigned short* __restrict__ h1, float* __restrict__ c1,
    float* __restrict__ FHL,
    const float* __restrict__ bsi, const float* __restrict__ bsh) {
  __shared__ alignas(16) unsigned short As[2][128 * 64];
  __shared__ alignas(16) unsigned short Bs[2][160 * 64];
  int bx, by; swz_blk(bx, by);
  LANE_SETUP
  const int rowBase = by * 128;
  const unsigned short* Arow = AinL + (size_t)rowBase * 320;
  const unsigned short* Brow = Bt + (size_t)bx * 160 * 320;
  f32x4 acc[4][5] = {};
  const int m = (bx * 2 + wc) * 16 + m16;

  float bi = bsi[m] + bsh[m];
  float bg = bsi[512 + m] + bsh[512 + m];
  float bo = bsi[768 + m] + bsh[768 + m];

  STAGE(As[0], Arow, 320, 128, 0)
  STAGE(Bs[0], Brow, 320, 160, 0)
#pragma unroll
  for (int ti = 0; ti < 5; ++ti) {
    if (ti < 4) {
      STAGE(As[(ti + 1) & 1], Arow, 320, 128, (ti + 1) * 64)
      STAGE(Bs[(ti + 1) & 1], Brow, 320, 160, (ti + 1) * 64)
      STEP_SYNC(9)
    } else {
      STEP_SYNC(0)
    }
    MFMA_BODY(As[ti & 1], Bs[ti & 1], 5, 80)
    __builtin_amdgcn_s_barrier();
  }

#pragma unroll
  for (int i = 0; i < 4; ++i)
#pragma unroll
    for (int r2 = 0; r2 < 4; ++r2) {
      int r = rowBase + wm + i * 16 + q * 4 + r2;
      float ii = sigf(acc[i][0][r2] + bi);
      float gg = tanh_a(acc[i][2][r2] + bg);
      float oo = sigf(acc[i][3][r2] + bo);
      float cv = ii * gg;
      size_t o = (size_t)r * 256 + m;
      h1[o] = f2bf(oo * tanh_a(cv));
      c1[o] = cv;
      FHL[o] = acc[i][4][r2];
    }
}

// ---------------------------------------------------------------------------
// GEMM2 + cell2 epilogue. A = [h1 | AinR] (crows x 576), B = WG2t.
__global__ __launch_bounds__(256, 2) void k_gemm2(
    const unsigned short* __restrict__ h1, const unsigned short* __restrict__ AinR,
    const unsigned short* __restrict__ Bt,
    const float* __restrict__ c1, unsigned short* __restrict__ HT,
    float* __restrict__ FHR,
    const float* __restrict__ bsi, const float* __restrict__ bsh) {
  __shared__ alignas(16) unsigned short As[2][128 * 64];
  __shared__ alignas(16) unsigned short Bs[2][160 * 64];
  int bx, by; swz_blk(bx, by);
  LANE_SETUP
  const int rowBase = by * 128;
  const unsigned short* Brow = Bt + (size_t)bx * 160 * 576;
  f32x4 acc[4][5] = {};
  const int m = (bx * 2 + wc) * 16 + m16;

  float b0 = bsi[m] + bsh[m];
  float b1 = bsi[256 + m] + bsh[256 + m];
  float b2 = bsi[512 + m] + bsh[512 + m];
  float b3 = bsi[768 + m] + bsh[768 + m];

  float pc[4][4];

  auto stageA = [&](unsigned short* dst, int kb) {
    if (kb < 256) {
      const unsigned short* Arow = h1 + (size_t)rowBase * 256;
#pragma unroll
      for (int c = 0; c < 4; ++c) {
        int row8 = wave * 32 + c * 8;
        load16_lds(Arow + (size_t)(row8 + l8) * 256 + kb + gsw, &dst[row8 * 64]);
      }
    } else {
      const unsigned short* Arow = AinR + (size_t)rowBase * 320;
      int k0 = kb - 256;
#pragma unroll
      for (int c = 0; c < 4; ++c) {
        int row8 = wave * 32 + c * 8;
        load16_lds(Arow + (size_t)(row8 + l8) * 320 + k0 + gsw, &dst[row8 * 64]);
      }
    }
  };

  stageA(As[0], 0);
  STAGE(Bs[0], Brow, 576, 160, 0)
#pragma unroll
  for (int ti = 0; ti < 9; ++ti) {
    if (ti < 8) {
      stageA(As[(ti + 1) & 1], (ti + 1) * 64);
      STAGE(Bs[(ti + 1) & 1], Brow, 576, 160, (ti + 1) * 64)
      STEP_SYNC(9)
      if (ti == 7) {
#pragma unroll
        for (int i = 0; i < 4; ++i)
#pragma unroll
          for (int r2 = 0; r2 < 4; ++r2) {
            int r = rowBase + wm + i * 16 + q * 4 + r2;
            pc[i][r2] = c1[(size_t)r * 256 + m];
          }
      }
    } else {
      STEP_SYNC(16)
    }
    MFMA_BODY(As[ti & 1], Bs[ti & 1], 5, 80)
    __builtin_amdgcn_s_barrier();
  }

#pragma unroll
  for (int i = 0; i < 4; ++i)
#pragma unroll
    for (int r2 = 0; r2 < 4; ++r2) {
      int r = rowBase + wm + i * 16 + q * 4 + r2;
      size_t o = (size_t)r * 256 + m;
      float ii = sigf(acc[i][0][r2] + b0);
      float ff = sigf(acc[i][1][r2] + b1);
      float gg = tanh_a(acc[i][2][r2] + b2);
      float oo = sigf(acc[i][3][r2] + b3);
      float c2 = ff * pc[i][r2] + ii * gg;
      HT[o] = f2bf(oo * tanh_a(c2));
      FHR[o] = acc[i][4][r2];
    }
}

// ---------------------------------------------------------------------------
// GEMM3 + node-gate epilogue. A = [HT | xbf-slice] (crows x 768), B = WEX2t.
__global__ __launch_bounds__(256, 2) void k_gemm3(
    const unsigned short* __restrict__ HT, const unsigned short* __restrict__ xnode,
    const unsigned short* __restrict__ Bt,
    const float* __restrict__ FHL, const float* __restrict__ FHR,
    float* __restrict__ cbuf, unsigned short* __restrict__ Ain,
    const float* __restrict__ rel, float* __restrict__ out,
    const float* __restrict__ bix, const float* __restrict__ bih,
    const float* __restrict__ bux, const float* __restrict__ buh,
    const float* __restrict__ box, const float* __restrict__ boh,
    const float* __restrict__ bfx, const float* __restrict__ bfh,
    int base, int v0, int n, int lvl) {
  __shared__ alignas(16) unsigned short As[2][128 * 64];
  __shared__ alignas(16) unsigned short Bs[2][128 * 64];
  int bx, by; swz_blk(bx, by);
  LANE_SETUP
  const int rowBase = by * 128;
  const unsigned short* Brow = Bt + (size_t)bx * 128 * 768;
  f32x4 acc[4][4] = {};
  const int m = (bx * 2 + wc) * 16 + m16;

  float bi = bix[m] + bih[m];
  float bu = bux[m] + buh[m];
  float bo = box[m] + boh[m];
  float bf = bfx[m] + bfh[m];

  float pfl[4][4], pfr[4][4], pc0[4][4], pc1v[4][4];

  auto stageA = [&](unsigned short* dst, int kb) {
    if (kb < 256) {
      const unsigned short* Arow = HT + (size_t)rowBase * 256;
#pragma unroll
      for (int c = 0; c < 4; ++c) {
        int row8 = wave * 32 + c * 8;
        load16_lds(Arow + (size_t)(row8 + l8) * 256 + kb + gsw, &dst[row8 * 64]);
      }
    } else {
      const unsigned short* Arow = xnode + (size_t)rowBase * 512;
      int k0 = kb - 256;
#pragma unroll
      for (int c = 0; c < 4; ++c) {
        int row8 = wave * 32 + c * 8;
        load16_lds(Arow + (size_t)(row8 + l8) * 512 + k0 + gsw, &dst[row8 * 64]);
      }
    }
  };

  stageA(As[0], 0);
  STAGE(Bs[0], Brow, 768, 128, 0)
#pragma unroll
  for (int ti = 0; ti < 12; ++ti) {
    if (ti < 11) {
      stageA(As[(ti + 1) & 1], (ti + 1) * 64);
      STAGE(Bs[(ti + 1) & 1], Brow, 768, 128, (ti + 1) * 64)
      STEP_SYNC(8)
      if (ti == 10) {
#pragma unroll
        for (int i = 0; i < 4; ++i)
#pragma unroll
          for (int r2 = 0; r2 < 4; ++r2) {
            int r = rowBase + wm + i * 16 + q * 4 + r2;
            int b = r & 127;
            int node = base + v0 + (r >> 7);
            size_t o = (size_t)r * 256 + m;
            size_t co = ((size_t)(2 * node + 1) * 128 + b) * 256 + m;
            pfl[i][r2] = FHL[o];
            pfr[i][r2] = FHR[o];
            pc0[i][r2] = cbuf[co];
            pc1v[i][r2] = cbuf[co + 32768];
          }
      }
    } else {
      STEP_SYNC(63)
    }
    MFMA_BODY(As[ti & 1], Bs[ti & 1], 4, 64)
    __builtin_amdgcn_s_barrier();
  }

#pragma unroll
  for (int i = 0; i < 4; ++i)
#pragma unroll
    for (int r2 = 0; r2 < 4; ++r2) {
      int r = rowBase + wm + i * 16 + q * 4 + r2;
      int vloc = r >> 7, b = r & 127;
      int vg = v0 + vloc;
      int node = base + vg;
      float pf = acc[i][3][r2] + bf;
      float f0 = sigf(pf + pfl[i][r2]);
      float f1 = sigf(pf + pfr[i][r2]);
      float ii = sigf(acc[i][0][r2] + bi);
      float uu = tanh_a(acc[i][1][r2] + bu);
      float oo = sigf(acc[i][2][r2] + bo);
      float cc = ii * uu + f0 * pc0[i][r2] + f1 * pc1v[i][r2];
      float hh = oo * tanh_a(cc);
      if (lvl == 0) {
        out[b * 256 + m] = hh;
      } else {
        cbuf[((size_t)node * 128 + b) * 256 + m] = cc;
        int rowA = (vg & 1) * (n >> 1) * 128 + (vg >> 1) * 128 + b;
        Ain[(size_t)rowA * 320 + m] = f2bf(hh);
        if (m < 64)
          Ain[(size_t)rowA * 320 + 256 + m] = f2bf(rel[((size_t)b * NNODE + node) * 64 + m]);
      }
    }
}

// ---------------------------------------------------------------------------
// Leaf GEMM + epilogue, multi-row-tile (RT=4). Grid (8,64); block handles
// tiles ty = by*4 + r. Next tile's k=0 staged during the previous tile's
// last step; epilogue overlaps the staging latency.
__global__ __launch_bounds__(256, 2) void k_leaf(
    const unsigned short* __restrict__ xleaf, const unsigned short* __restrict__ Bt,
    float* __restrict__ cbuf, unsigned short* __restrict__ Ain,
    const float* __restrict__ rel,
    const float* __restrict__ bix, const float* __restrict__ bih,
    const float* __restrict__ bux, const float* __restrict__ buh,
    const float* __restrict__ box, const float* __restrict__ boh) {
  __shared__ alignas(16) unsigned short As[2][128 * 64];
  __shared__ alignas(16) unsigned short Bs[2][96 * 64];
  int bx, by; swz_blk(bx, by);
  LANE_SETUP
  const int RT = 4;
  const unsigned short* Brow = Bt + (size_t)bx * 96 * 512;
  const int m = (bx * 2 + wc) * 16 + m16;

  float bi = bix[m] + bih[m];
  float bu = bux[m] + buh[m];
  float bo = box[m] + boh[m];

  // Prologue: tile (by*RT), k=0.
  {
    const unsigned short* Arow = xleaf + (size_t)(by * RT) * 128 * 512;
    STAGE(As[0], Arow, 512, 128, 0)
#pragma unroll
    for (int c = 0; c < 3; ++c) {
      int row8 = wave * 24 + c * 8;
      load16_lds(Brow + (size_t)(row8 + l8) * 512 + 0 + gsw, &Bs[0][row8 * 64]);
    }
  }

  for (int r = 0; r < RT; ++r) {
    const int ty = by * RT + r;
    const unsigned short* Arow = xleaf + (size_t)ty * 128 * 512;
    const unsigned short* ArowN = xleaf + (size_t)(ty + 1) * 128 * 512;
    f32x4 acc[4][3] = {};
#pragma unroll
    for (int ti = 0; ti < 8; ++ti) {
      if (ti < 7) {
        int kn = (ti + 1) * 64;
        STAGE(As[(ti + 1) & 1], Arow, 512, 128, kn)
#pragma unroll
        for (int c = 0; c < 3; ++c) {
          int row8 = wave * 24 + c * 8;
          load16_lds(Brow + (size_t)(row8 + l8) * 512 + kn + gsw, &Bs[(ti + 1) & 1][row8 * 64]);
        }
        STEP_SYNC(7)
      } else if (r + 1 < RT) {
        // Next tile's k=0 into buf0; its latency hides under this epilogue.
        STAGE(As[0], ArowN, 512, 128, 0)
#pragma unroll
        for (int c = 0; c < 3; ++c) {
          int row8 = wave * 24 + c * 8;
          load16_lds(Brow + (size_t)(row8 + l8) * 512 + 0 + gsw, &Bs[0][row8 * 64]);
        }
        STEP_SYNC(7)
      } else {
        STEP_SYNC(0)
      }
      MFMA_BODY(As[ti & 1], Bs[ti & 1], 3, 48)
      __builtin_amdgcn_s_barrier();
    }

    // Epilogue for tile ty.
#pragma unroll
    for (int i = 0; i < 4; ++i)
#pragma unroll
      for (int r2 = 0; r2 < 4; ++r2) {
        int lr = wm + i * 16 + q * 4 + r2;
        int b = lr;
        int node = 255 + ty;
        float ii = sigf(acc[i][0][r2] + bi);
        float uu = tanh_a(acc[i][1][r2] + bu);
        float oo = sigf(acc[i][2][r2] + bo);
        float cc = ii * uu;
        float hh = oo * tanh_a(cc);
        cbuf[((size_t)node * 128 + b) * 256 + m] = cc;
        int rowA = (ty & 1) * 16384 + (ty >> 1) * 128 + b;
        Ain[(size_t)rowA * 320 + m] = f2bf(hh);
        if (m < 64)
          Ain[(size_t)rowA * 320 + 256 + m] = f2bf(rel[((size_t)b * NNODE + node) * 64 + m]);
      }
  }
}

// ---------------------------------------------------------------------------
// Fused tail: levels 4..0 in one launch, grid (8,16) = 128 blocks (all
// co-resident), grid barrier between the 15 GEMM phases.
__global__ __launch_bounds__(256, 2) void k_tail(
    unsigned short* __restrict__ Ain, const unsigned short* __restrict__ xbf,
    const unsigned short* __restrict__ WA2t, const unsigned short* __restrict__ WG2t,
    const unsigned short* __restrict__ WEX2t,
    unsigned short* __restrict__ h1, float* __restrict__ c1,
    float* __restrict__ FHL, float* __restrict__ FHR,
    unsigned short* __restrict__ HT, float* __restrict__ cbuf,
    const float* __restrict__ rel, float* __restrict__ out,
    const float* __restrict__ bsi, const float* __restrict__ bsh,
    const float* __restrict__ bix, const float* __restrict__ bih,
    const float* __restrict__ bux, const float* __restrict__ buh,
    const float* __restrict__ box, const float* __restrict__ boh,
    const float* __restrict__ bfx, const float* __restrict__ bfh,
    unsigned* __restrict__ bar) {
  __shared__ alignas(16) unsigned short As[2][128 * 64];
  __shared__ alignas(16) unsigned short Bs[2][160 * 64];
  const int bx = blockIdx.x, by = blockIdx.y;
  LANE_SETUP
  const int m = (bx * 2 + wc) * 16 + m16;

  for (int lvl = 4; lvl >= 0; --lvl) {
    const int n = 1 << lvl;
    const int base = n - 1;

    if (by < n) {  // ---- g1: A = AinL rows [by*128), K=320, B = WA2t ----
      const unsigned short* Arow = Ain + (size_t)by * 128 * 320;
      const unsigned short* Brow = WA2t + (size_t)bx * 160 * 320;
      float bi = bsi[m] + bsh[m];
      float bg = bsi[512 + m] + bsh[512 + m];
      float bo = bsi[768 + m] + bsh[768 + m];
      f32x4 acc[4][5] = {};
      STAGE(As[0], Arow, 320, 128, 0)
      STAGE(Bs[0], Brow, 320, 160, 0)
#pragma unroll
      for (int ti = 0; ti < 5; ++ti) {
        if (ti < 4) {
          STAGE(As[(ti + 1) & 1], Arow, 320, 128, (ti + 1) * 64)
          STAGE(Bs[(ti + 1) & 1], Brow, 320, 160, (ti + 1) * 64)
          STEP_SYNC(9)
        } else {
          STEP_SYNC(0)
        }
        MFMA_BODY(As[ti & 1], Bs[ti & 1], 5, 80)
        __builtin_amdgcn_s_barrier();
      }
#pragma unroll
      for (int i = 0; i < 4; ++i)
#pragma unroll
        for (int r2 = 0; r2 < 4; ++r2) {
          int r = by * 128 + wm + i * 16 + q * 4 + r2;
          float ii = sigf(acc[i][0][r2] + bi);
          float gg = tanh_a(acc[i][2][r2] + bg);
          float oo = sigf(acc[i][3][r2] + bo);
          float cv = ii * gg;
          size_t o = (size_t)r * 256 + m;
          h1[o] = f2bf(oo * tanh_a(cv));
          c1[o] = cv;
          FHL[o] = acc[i][4][r2];
        }
    }
    gridbar(bar, bar + 1);

    if (by < n) {  // ---- g2: A = [h1 | AinR], K=576, B = WG2t ----
      const unsigned short* Brow = WG2t + (size_t)bx * 160 * 576;
      float b0 = bsi[m] + bsh[m];
      float b1 = bsi[256 + m] + bsh[256 + m];
      float b2 = bsi[512 + m] + bsh[512 + m];
      float b3 = bsi[768 + m] + bsh[768 + m];
      f32x4 acc[4][5] = {};
      auto stA = [&](unsigned short* dst, int kb) {
        if (kb < 256) {
          const unsigned short* Arow = h1 + (size_t)by * 128 * 256;
#pragma unroll
          for (int c = 0; c < 4; ++c) {
            int row8 = wave * 32 + c * 8;
            load16_lds(Arow + (size_t)(row8 + l8) * 256 + kb + gsw, &dst[row8 * 64]);
          }
        } else {
          const unsigned short* Arow = Ain + (size_t)(n + by) * 128 * 320;
          int k0 = kb - 256;
#pragma unroll
          for (int c = 0; c < 4; ++c) {
            int row8 = wave * 32 + c * 8;
            load16_lds(Arow + (size_t)(row8 + l8) * 320 + k0 + gsw, &dst[row8 * 64]);
          }
        }
      };
      stA(As[0], 0);
      STAGE(Bs[0], Brow, 576, 160, 0)
#pragma unroll
      for (int ti = 0; ti < 9; ++ti) {
        if (ti < 8) {
          stA(As[(ti + 1) & 1], (ti + 1) * 64);
          STAGE(Bs[(ti + 1) & 1], Brow, 576, 160, (ti + 1) * 64)
          STEP_SYNC(9)
        } else {
          STEP_SYNC(0)
        }
        MFMA_BODY(As[ti & 1], Bs[ti & 1], 5, 80)
        __builtin_amdgcn_s_barrier();
      }
#pragma unroll
      for (int i = 0; i < 4; ++i)
#pragma unroll
        for (int r2 = 0; r2 < 4; ++r2) {
          int r = by * 128 + wm + i * 16 + q * 4 + r2;
          size_t o = (size_t)r * 256 + m;
          float ii = sigf(acc[i][0][r2] + b0);
          float ff = sigf(acc[i][1][r2] + b1);
          float gg = tanh_a(acc[i][2][r2] + b2);
          float oo = sigf(acc[i][3][r2] + b3);
          float c2 = ff * c1[o] + ii * gg;
          HT[o] = f2bf(oo * tanh_a(c2));
          FHR[o] = acc[i][4][r2];
        }
    }
    gridbar(bar, bar + 1);

    if (by < n) {  // ---- g3: A = [HT | xnode], K=768, B = WEX2t ----
      const unsigned short* xnode = xbf + (size_t)base * 128 * 512;
      const unsigned short* Brow = WEX2t + (size_t)bx * 128 * 768;
      float bi = bix[m] + bih[m];
      float bu = bux[m] + buh[m];
      float bo = box[m] + boh[m];
      float bf = bfx[m] + bfh[m];
      f32x4 acc[4][4] = {};
      auto stA = [&](unsigned short* dst, int kb) {
        if (kb < 256) {
          const unsigned short* Arow = HT + (size_t)by * 128 * 256;
#pragma unroll
          for (int c = 0; c < 4; ++c) {
            int row8 = wave * 32 + c * 8;
            load16_lds(Arow + (size_t)(row8 + l8) * 256 + kb + gsw, &dst[row8 * 64]);
          }
        } else {
          const unsigned short* Arow = xnode + (size_t)by * 128 * 512;
          int k0 = kb - 256;
#pragma unroll
          for (int c = 0; c < 4; ++c) {
            int row8 = wave * 32 + c * 8;
            load16_lds(Arow + (size_t)(row8 + l8) * 512 + k0 + gsw, &dst[row8 * 64]);
          }
        }
      };
      stA(As[0], 0);
      STAGE(Bs[0], Brow, 768, 128, 0)
#pragma unroll
      for (int ti = 0; ti < 12; ++ti) {
        if (ti < 11) {
          stA(As[(ti + 1) & 1], (ti + 1) * 64);
          STAGE(Bs[(ti + 1) & 1], Brow, 768, 128, (ti + 1) * 64)
          STEP_SYNC(8)
        } else {
          STEP_SYNC(0)
        }
        MFMA_BODY(As[ti & 1], Bs[ti & 1], 4, 64)
        __builtin_amdgcn_s_barrier();
      }
#pragma unroll
      for (int i = 0; i < 4; ++i)
#pragma unroll
        for (int r2 = 0; r2 < 4; ++r2) {
          int lr = wm + i * 16 + q * 4 + r2;
          int b = lr;
          int node = base + by;
          size_t o = (size_t)(by * 128 + lr) * 256 + m;
          size_t co = ((size_t)(2 * node + 1) * 128 + b) * 256 + m;
          float pf = acc[i][3][r2] + bf;
          float f0 = sigf(pf + FHL[o]);
          float f1 = sigf(pf + FHR[o]);
          float ii = sigf(acc[i][0][r2] + bi);
          float uu = tanh_a(acc[i][1][r2] + bu);
          float oo = sigf(acc[i][2][r2] + bo);
          float cc = ii * uu + f0 * cbuf[co] + f1 * cbuf[co + 32768];
          float hh = oo * tanh_a(cc);
          if (lvl == 0) {
            out[b * 256 + m] = hh;
          } else {
            cbuf[((size_t)node * 128 + b) * 256 + m] = cc;
            int rowA = (by & 1) * (n >> 1) * 128 + (by >> 1) * 128 + b;
            Ain[(size_t)rowA * 320 + m] = f2bf(hh);
            if (m < 64)
              Ain[(size_t)rowA * 320 + 256 + m] = f2bf(rel[((size_t)b * NNODE + node) * 64 + m]);
          }
        }
    }
    if (lvl > 0) gridbar(bar, bar + 1);
  }
}

// ---------------------------------------------------------------------------
extern "C" void kernel_launch(void* const* d_in, const int* in_sizes, int n_in,
                              void* d_out, int out_size, void* d_ws, size_t ws_size,
                              hipStream_t stream) {
  const float* wte = (const float*)d_in[0];
  const float* rel = (const float*)d_in[1];
  const float* Wix = (const float*)d_in[3];
  const float* bix = (const float*)d_in[4];
  const float* Wfx = (const float*)d_in[5];
  const float* bfx = (const float*)d_in[6];
  const float* Wux = (const float*)d_in[7];
  const float* bux = (const float*)d_in[8];
  const float* Wox = (const float*)d_in[9];
  const float* box = (const float*)d_in[10];
  const float* Wih = (const float*)d_in[11];
  const float* bih = (const float*)d_in[12];
  const float* Wfh = (const float*)d_in[13];
  const float* bfh = (const float*)d_in[14];
  const float* Wuh = (const float*)d_in[15];
  const float* buh = (const float*)d_in[16];
  const float* Woh = (const float*)d_in[17];
  const float* boh = (const float*)d_in[18];
  const float* Wsi = (const float*)d_in[19];
  const float* Wsh = (const float*)d_in[20];
  const float* bsi = (const float*)d_in[21];
  const float* bsh = (const float*)d_in[22];
  float* out = (float*)d_out;
  (void)in_sizes; (void)n_in; (void)out_size;

  int INT_MAXN;
  if (ws_size >= (size_t)310 * 1024 * 1024)      INT_MAXN = 128;
  else if (ws_size >= (size_t)200 * 1024 * 1024) INT_MAXN = 32;
  else                                           INT_MAXN = 8;
  const int crowsMax = INT_MAXN * 128;

  char* ws = (char*)d_ws;
  size_t off = 0;
  auto alloc = [&](size_t bytes) {
    size_t o = off; off += (bytes + 255) & ~(size_t)255; return o;
  };
  unsigned short* xbf  = (unsigned short*)(ws + alloc((size_t)NNODE * 128 * 512 * 2));
  float*          cbuf = (float*)         (ws + alloc((size_t)NNODE * 128 * 256 * 4));
  unsigned short* Ain  = (unsigned short*)(ws + alloc((size_t)32768 * 320 * 2));
  unsigned short* WL2t = (unsigned short*)(ws + alloc((size_t)768 * 512 * 2));
  unsigned short* WA2t = (unsigned short*)(ws + alloc((size_t)1280 * 320 * 2));
  unsigned short* WG2t = (unsigned short*)(ws + alloc((size_t)1280 * 576 * 2));
  unsigned short* WEX2t= (unsigned short*)(ws + alloc((size_t)1024 * 768 * 2));
  unsigned short* h1   = (unsigned short*)(ws + alloc((size_t)crowsMax * 256 * 2));
  float*          c1   = (float*)         (ws + alloc((size_t)crowsMax * 256 * 4));
  float*          FHL  = (float*)         (ws + alloc((size_t)crowsMax * 256 * 4));
  float*          FHR  = (float*)         (ws + alloc((size_t)crowsMax * 256 * 4));
  unsigned short* HT   = (unsigned short*)(ws + alloc((size_t)crowsMax * 256 * 2));
  unsigned*       bar  = (unsigned*)      (ws + alloc(256));

  k_prep_x<<<32704, 256, 0, stream>>>(wte, xbf, bar);
  k_prep_w<<<9088, 256, 0, stream>>>(Wix, Wux, Wox, Wfx, Wih, Wuh, Woh, Wfh,
                                     Wsi, Wsh, WL2t, WA2t, WG2t, WEX2t);

  // Leaves: fused GEMM over xbf rows [255*128, 511*128), 4 row-tiles/block.
  k_leaf<<<dim3(8, 64), 256, 0, stream>>>(xbf + (size_t)255 * 128 * 512, WL2t,
                                          cbuf, Ain, rel, bix, bih, bux, buh, box, boh);

  const bool fuse = (INT_MAXN >= 16);
  const int lvlMin = fuse ? 5 : 0;
  for (int lvl = 7; lvl >= lvlMin; --lvl) {
    int n = 1 << lvl;
    int base = n - 1;
    int cn = (n < INT_MAXN) ? n : INT_MAXN;
    for (int v0 = 0; v0 < n; v0 += cn) {
      const unsigned short* AinL = Ain + (size_t)(v0 * 128) * 320;
      const unsigned short* AinR = Ain + (size_t)((n + v0) * 128) * 320;
      const unsigned short* xnode = xbf + (size_t)(base + v0) * 128 * 512;
      k_gemm1<<<dim3(8, cn), 256, 0, stream>>>(AinL, WA2t, h1, c1, FHL, bsi, bsh);
      k_gemm2<<<dim3(8, cn), 256, 0, stream>>>(h1, AinR, WG2t, c1, HT, FHR, bsi, bsh);
      k_gemm3<<<dim3(8, cn), 256, 0, stream>>>(HT, xnode, WEX2t, FHL, FHR, cbuf, Ain,
                                               rel, out, bix, bih, bux, buh, box, boh,
                                               bfx, bfh, base, v0, n, lvl);
    }
  }
  if (fuse) {
    k_tail<<<dim3(8, 16), 256, 0, stream>>>(Ain, xbf, WA2t, WG2t, WEX2t,
                                            h1, c1, FHL, FHR, HT, cbuf, rel, out,
                                            bsi, bsh, bix, bih, bux, buh, box, boh,
                                            bfx, bfh, bar);
  }
}

// Round 7
// 1207.315 us; speedup vs baseline: 1.5138x; 1.5138x over previous
//
#include <hip/hip_runtime.h>
#include <math.h>

// N=511 complete binary tree: nodes 0..254 internal, 255..510 leaves.
// B=128, M=256, IN=512, R=64.
// Gate-interleaved bf16 weight layouts fuse every LSTM-cell epilogue into its
// producing GEMM. Staging via global_load_lds width=16; unpadded LDS tiles
// with XOR k-slot swizzle compensated in the per-lane global source address.
// R5: fast exp2/rcp transcendentals + XCD block remap. R6/7: dbuf +
// counted-vmcnt K-loop. R8: epilogue operand prefetch. R9: PR eliminated via
// [h1|AinR] K-extension. R10: k_tail (lvl4..0 fused, grid barrier) + k_leaf
// RT=4. R10 FAILED: ACQUIRE inside the spin loop = per-poll L1/L2 invalidate
// from 127 spinning blocks -> cache-invalidation storm (k_tail 1300 us,
// FETCH 136 MB). R11 (this): spin on RELAXED agent load (sc1, reads the
// coherence point, no invalidate), s_sleep(32) poll, ONE acquire fence after
// exit; release fence before the counter RMW. Everything else unchanged.
#define NNODE 511

typedef short s16x8 __attribute__((ext_vector_type(8)));
typedef float f32x4 __attribute__((ext_vector_type(4)));

__device__ __forceinline__ unsigned short f2bf(float f) {
  unsigned int u = __builtin_bit_cast(unsigned int, f);
  u += 0x7fffu + ((u >> 16) & 1u);           // RNE
  return (unsigned short)(u >> 16);
}
__device__ __forceinline__ float sigf(float x) {
  float e = __builtin_amdgcn_exp2f(-1.442695040888963f * x);
  return __builtin_amdgcn_rcpf(1.0f + e);
}
__device__ __forceinline__ float tanh_a(float x) {
  float e = __builtin_amdgcn_exp2f(2.885390081777927f * x);
  return 1.0f - 2.0f * __builtin_amdgcn_rcpf(1.0f + e);
}

__device__ __forceinline__ void load16_lds(const unsigned short* g, unsigned short* l) {
  __builtin_amdgcn_global_load_lds(
      (const __attribute__((address_space(1))) void*)g,
      (__attribute__((address_space(3))) void*)l, 16, 0, 0);
}

template<int N> __device__ __forceinline__ void s_wait_vmcnt() {
  asm volatile("s_waitcnt vmcnt(%0)" :: "n"(N) : "memory");
}

// XCD-aware block remap (bijective when ny%8==0; tail launches L2-fit).
__device__ __forceinline__ void swz_blk(int& bx, int& by) {
  bx = blockIdx.x; by = blockIdx.y;
  int ny = gridDim.y;
  if ((ny & 7) == 0) {
    int lin = by * 8 + bx;
    int w = lin >> 3;
    by = (lin & 7) * (ny >> 3) + (w >> 3);
    bx = w & 7;
  }
}

// Device-scope grid barrier. Release fence (once) -> counter RMW; waiters
// spin on a RELAXED agent load (sc1: reads coherence point, NO invalidate),
// then ONE acquire fence after exit invalidates local caches.
__device__ __forceinline__ void gridbar(unsigned* cnt, unsigned* gen) {
  __syncthreads();
  if (threadIdx.x == 0) {
    unsigned nb = gridDim.x * gridDim.y;
    unsigned g = __hip_atomic_load(gen, __ATOMIC_RELAXED, __HIP_MEMORY_SCOPE_AGENT);
    __builtin_amdgcn_fence(__ATOMIC_RELEASE, "agent");   // write-back our stores
    unsigned a = __hip_atomic_fetch_add(cnt, 1u, __ATOMIC_RELAXED, __HIP_MEMORY_SCOPE_AGENT);
    if (a == nb - 1u) {
      __hip_atomic_store(cnt, 0u, __ATOMIC_RELAXED, __HIP_MEMORY_SCOPE_AGENT);
      __hip_atomic_store(gen, g + 1u, __ATOMIC_RELAXED, __HIP_MEMORY_SCOPE_AGENT);
    } else {
      while (__hip_atomic_load(gen, __ATOMIC_RELAXED, __HIP_MEMORY_SCOPE_AGENT) == g) {
        __builtin_amdgcn_s_sleep(32);
      }
    }
    __builtin_amdgcn_fence(__ATOMIC_ACQUIRE, "agent");   // one invalidate
  }
  __syncthreads();
}

// ---------------------------------------------------------------------------
// wte (B,511,512) fp32 -> xbf (node,b,k) bf16, node-major. Also zeroes the
// grid-barrier counters (workspace is re-poisoned every iteration).
__global__ void k_prep_x(const float* __restrict__ w, unsigned short* __restrict__ xbf,
                         unsigned* __restrict__ bar) {
  if (blockIdx.x == 0 && threadIdx.x == 0) { bar[0] = 0u; bar[1] = 0u; }
  int o = (blockIdx.x * 256 + threadIdx.x) * 4;
  int node = o >> 16;
  int b = (o >> 9) & 127;
  int k = o & 511;
  const float4 v = *(const float4*)(w + ((size_t)b * NNODE + node) * 512 + k);
  unsigned int p0 = (unsigned int)f2bf(v.x) | ((unsigned int)f2bf(v.y) << 16);
  unsigned int p1 = (unsigned int)f2bf(v.z) | ((unsigned int)f2bf(v.w) << 16);
  *(uint2*)(xbf + o) = make_uint2(p0, p1);
}

// ---------------------------------------------------------------------------
// Gate-interleaved transposed weights:
//  WL2t (768,512):  c = 48G+16g+mi, g in {i,u,o}
//  WA2t (1280,320): c = 80G+16g+mi, g in {i,f,g,o,fh}
//  WG2t (1280,576): c = 80G+16g+mi; g<4: k<256 Wsh, k>=256 Wsi; g==4 Wfh on 256..511
//  WEX2t(1024,768): c = 64G+16g+mi, g in {i,u,o,f}; k<256 h-w, k>=256 x-w
__global__ void k_prep_w(const float* __restrict__ Wix, const float* __restrict__ Wux,
                         const float* __restrict__ Wox, const float* __restrict__ Wfx,
                         const float* __restrict__ Wih, const float* __restrict__ Wuh,
                         const float* __restrict__ Woh, const float* __restrict__ Wfh,
                         const float* __restrict__ Wsi, const float* __restrict__ Wsh,
                         unsigned short* __restrict__ WL2t, unsigned short* __restrict__ WA2t,
                         unsigned short* __restrict__ WG2t, unsigned short* __restrict__ WEX2t) {
  int idx = blockIdx.x * 256 + threadIdx.x;
  if (idx < 393216) {                       // WL2t 768*512
    int c = idx >> 9, k = idx & 511;
    int G = c / 48, rem = c - G * 48, g = rem >> 4, mi = rem & 15, m = G * 16 + mi;
    const float* W = (g == 0) ? Wix : (g == 1) ? Wux : Wox;
    WL2t[idx] = f2bf(W[k * 256 + m]);
  } else if (idx < 802816) {                // WA2t 1280*320
    int o = idx - 393216;
    int c = o / 320, k = o - c * 320;
    int G = c / 80, rem = c - G * 80, g = rem >> 4, mi = rem & 15, m = G * 16 + mi;
    float v;
    if (g < 4) v = Wsi[k * 1024 + g * 256 + m];
    else       v = (k < 256) ? Wfh[k * 256 + m] : 0.0f;
    WA2t[o] = f2bf(v);
  } else if (idx < 1540096) {               // WG2t 1280*576
    int o = idx - 802816;
    int c = o / 576, k = o - c * 576;
    int G = c / 80, rem = c - G * 80, g = rem >> 4, mi = rem & 15, m = G * 16 + mi;
    float v;
    if (g < 4) v = (k < 256) ? Wsh[k * 1024 + g * 256 + m]
                             : Wsi[(k - 256) * 1024 + g * 256 + m];
    else       v = (k >= 256 && k < 512) ? Wfh[(k - 256) * 256 + m] : 0.0f;
    WG2t[o] = f2bf(v);
  } else if (idx < 2326528) {               // WEX2t 1024*768
    int o = idx - 1540096;
    int c = o / 768, k = o - c * 768;
    int G = c >> 6, rem = c & 63, g = rem >> 4, mi = rem & 15, m = G * 16 + mi;
    float v;
    if (k < 256) {
      v = (g == 0) ? Wih[k * 256 + m] : (g == 1) ? Wuh[k * 256 + m]
        : (g == 2) ? Woh[k * 256 + m] : 0.0f;
    } else {
      int k2 = k - 256;
      v = (g == 0) ? Wix[k2 * 256 + m] : (g == 1) ? Wux[k2 * 256 + m]
        : (g == 2) ? Wox[k2 * 256 + m] : Wfx[k2 * 256 + m];
    }
    WEX2t[o] = f2bf(v);
  }
}

// Swizzled MFMA inner step. sw(kk) = (kk | q*8) ^ ((m16&7)*8).
#define MFMA_BODY(AP, BP, NG, CW)                                             \
  _Pragma("unroll")                                                           \
  for (int kk = 0; kk < 64; kk += 32) {                                       \
    const int sw = (kk | (q * 8)) ^ ((m16 & 7) * 8);                          \
    s16x8 af[4], bfr[NG];                                                     \
    _Pragma("unroll")                                                         \
    for (int i = 0; i < 4; ++i)                                               \
      af[i] = *(const s16x8*)(&(AP)[(wm + i * 16 + m16) * 64 + sw]);          \
    _Pragma("unroll")                                                         \
    for (int j = 0; j < NG; ++j)                                              \
      bfr[j] = *(const s16x8*)(&(BP)[(wc * CW + j * 16 + m16) * 64 + sw]);    \
    _Pragma("unroll")                                                         \
    for (int i = 0; i < 4; ++i)                                               \
      _Pragma("unroll")                                                       \
      for (int j = 0; j < NG; ++j)                                            \
        acc[i][j] = __builtin_amdgcn_mfma_f32_16x16x32_bf16(af[i], bfr[j], acc[i][j], 0, 0, 0); \
  }

#define STAGE(DST, SRC, STRIDE, R, K0)                                        \
  _Pragma("unroll")                                                           \
  for (int c = 0; c < (R) / 32; ++c) {                                        \
    int row8 = wave * ((R) / 4) + c * 8;                                      \
    load16_lds(SRC + (size_t)(row8 + l8) * (STRIDE) + (K0) + gsw, &(DST)[row8 * 64]); \
  }

#define STEP_SYNC(VM)                                                         \
  s_wait_vmcnt<VM>();                                                         \
  __builtin_amdgcn_s_barrier();                                               \
  __builtin_amdgcn_sched_barrier(0);

#define LANE_SETUP                                                            \
  const int t = threadIdx.x;                                                  \
  const int wave = t >> 6, lane = t & 63;                                     \
  const int wm = (wave & 1) * 64, wc = wave >> 1;                             \
  const int m16 = lane & 15, q = lane >> 4;                                   \
  const int l8 = lane >> 3, l7 = lane & 7;                                    \
  const int gsw = ((l7 ^ l8) * 8);

// ---------------------------------------------------------------------------
// GEMM1 + cell1 epilogue. A = AinL (crows x 320 bf16), B = WA2t.
__global__ __launch_bounds__(256, 2) void k_gemm1(
    const unsigned short* __restrict__ AinL, const unsigned short* __restrict__ Bt,
    unsigned short* __restrict__ h1, float* __restrict__ c1,
    float* __restrict__ FHL,
    const float* __restrict__ bsi, const float* __restrict__ bsh) {
  __shared__ alignas(16) unsigned short As[2][128 * 64];
  __shared__ alignas(16) unsigned short Bs[2][160 * 64];
  int bx, by; swz_blk(bx, by);
  LANE_SETUP
  const int rowBase = by * 128;
  const unsigned short* Arow = AinL + (size_t)rowBase * 320;
  const unsigned short* Brow = Bt + (size_t)bx * 160 * 320;
  f32x4 acc[4][5] = {};
  const int m = (bx * 2 + wc) * 16 + m16;

  float bi = bsi[m] + bsh[m];
  float bg = bsi[512 + m] + bsh[512 + m];
  float bo = bsi[768 + m] + bsh[768 + m];

  STAGE(As[0], Arow, 320, 128, 0)
  STAGE(Bs[0], Brow, 320, 160, 0)
#pragma unroll
  for (int ti = 0; ti < 5; ++ti) {
    if (ti < 4) {
      STAGE(As[(ti + 1) & 1], Arow, 320, 128, (ti + 1) * 64)
      STAGE(Bs[(ti + 1) & 1], Brow, 320, 160, (ti + 1) * 64)
      STEP_SYNC(9)
    } else {
      STEP_SYNC(0)
    }
    MFMA_BODY(As[ti & 1], Bs[ti & 1], 5, 80)
    __builtin_amdgcn_s_barrier();
  }

#pragma unroll
  for (int i = 0; i < 4; ++i)
#pragma unroll
    for (int r2 = 0; r2 < 4; ++r2) {
      int r = rowBase + wm + i * 16 + q * 4 + r2;
      float ii = sigf(acc[i][0][r2] + bi);
      float gg = tanh_a(acc[i][2][r2] + bg);
      float oo = sigf(acc[i][3][r2] + bo);
      float cv = ii * gg;
      size_t o = (size_t)r * 256 + m;
      h1[o] = f2bf(oo * tanh_a(cv));
      c1[o] = cv;
      FHL[o] = acc[i][4][r2];
    }
}

// ---------------------------------------------------------------------------
// GEMM2 + cell2 epilogue. A = [h1 | AinR] (crows x 576), B = WG2t.
__global__ __launch_bounds__(256, 2) void k_gemm2(
    const unsigned short* __restrict__ h1, const unsigned short* __restrict__ AinR,
    const unsigned short* __restrict__ Bt,
    const float* __restrict__ c1, unsigned short* __restrict__ HT,
    float* __restrict__ FHR,
    const float* __restrict__ bsi, const float* __restrict__ bsh) {
  __shared__ alignas(16) unsigned short As[2][128 * 64];
  __shared__ alignas(16) unsigned short Bs[2][160 * 64];
  int bx, by; swz_blk(bx, by);
  LANE_SETUP
  const int rowBase = by * 128;
  const unsigned short* Brow = Bt + (size_t)bx * 160 * 576;
  f32x4 acc[4][5] = {};
  const int m = (bx * 2 + wc) * 16 + m16;

  float b0 = bsi[m] + bsh[m];
  float b1 = bsi[256 + m] + bsh[256 + m];
  float b2 = bsi[512 + m] + bsh[512 + m];
  float b3 = bsi[768 + m] + bsh[768 + m];

  float pc[4][4];

  auto stageA = [&](unsigned short* dst, int kb) {
    if (kb < 256) {
      const unsigned short* Arow = h1 + (size_t)rowBase * 256;
#pragma unroll
      for (int c = 0; c < 4; ++c) {
        int row8 = wave * 32 + c * 8;
        load16_lds(Arow + (size_t)(row8 + l8) * 256 + kb + gsw, &dst[row8 * 64]);
      }
    } else {
      const unsigned short* Arow = AinR + (size_t)rowBase * 320;
      int k0 = kb - 256;
#pragma unroll
      for (int c = 0; c < 4; ++c) {
        int row8 = wave * 32 + c * 8;
        load16_lds(Arow + (size_t)(row8 + l8) * 320 + k0 + gsw, &dst[row8 * 64]);
      }
    }
  };

  stageA(As[0], 0);
  STAGE(Bs[0], Brow, 576, 160, 0)
#pragma unroll
  for (int ti = 0; ti < 9; ++ti) {
    if (ti < 8) {
      stageA(As[(ti + 1) & 1], (ti + 1) * 64);
      STAGE(Bs[(ti + 1) & 1], Brow, 576, 160, (ti + 1) * 64)
      STEP_SYNC(9)
      if (ti == 7) {
#pragma unroll
        for (int i = 0; i < 4; ++i)
#pragma unroll
          for (int r2 = 0; r2 < 4; ++r2) {
            int r = rowBase + wm + i * 16 + q * 4 + r2;
            pc[i][r2] = c1[(size_t)r * 256 + m];
          }
      }
    } else {
      STEP_SYNC(16)
    }
    MFMA_BODY(As[ti & 1], Bs[ti & 1], 5, 80)
    __builtin_amdgcn_s_barrier();
  }

#pragma unroll
  for (int i = 0; i < 4; ++i)
#pragma unroll
    for (int r2 = 0; r2 < 4; ++r2) {
      int r = rowBase + wm + i * 16 + q * 4 + r2;
      size_t o = (size_t)r * 256 + m;
      float ii = sigf(acc[i][0][r2] + b0);
      float ff = sigf(acc[i][1][r2] + b1);
      float gg = tanh_a(acc[i][2][r2] + b2);
      float oo = sigf(acc[i][3][r2] + b3);
      float c2 = ff * pc[i][r2] + ii * gg;
      HT[o] = f2bf(oo * tanh_a(c2));
      FHR[o] = acc[i][4][r2];
    }
}

// ---------------------------------------------------------------------------
// GEMM3 + node-gate epilogue. A = [HT | xbf-slice] (crows x 768), B = WEX2t.
__global__ __launch_bounds__(256, 2) void k_gemm3(
    const unsigned short* __restrict__ HT, const unsigned short* __restrict__ xnode,
    const unsigned short* __restrict__ Bt,
    const float* __restrict__ FHL, const float* __restrict__ FHR,
    float* __restrict__ cbuf, unsigned short* __restrict__ Ain,
    const float* __restrict__ rel, float* __restrict__ out,
    const float* __restrict__ bix, const float* __restrict__ bih,
    const float* __restrict__ bux, const float* __restrict__ buh,
    const float* __restrict__ box, const float* __restrict__ boh,
    const float* __restrict__ bfx, const float* __restrict__ bfh,
    int base, int v0, int n, int lvl) {
  __shared__ alignas(16) unsigned short As[2][128 * 64];
  __shared__ alignas(16) unsigned short Bs[2][128 * 64];
  int bx, by; swz_blk(bx, by);
  LANE_SETUP
  const int rowBase = by * 128;
  const unsigned short* Brow = Bt + (size_t)bx * 128 * 768;
  f32x4 acc[4][4] = {};
  const int m = (bx * 2 + wc) * 16 + m16;

  float bi = bix[m] + bih[m];
  float bu = bux[m] + buh[m];
  float bo = box[m] + boh[m];
  float bf = bfx[m] + bfh[m];

  float pfl[4][4], pfr[4][4], pc0[4][4], pc1v[4][4];

  auto stageA = [&](unsigned short* dst, int kb) {
    if (kb < 256) {
      const unsigned short* Arow = HT + (size_t)rowBase * 256;
#pragma unroll
      for (int c = 0; c < 4; ++c) {
        int row8 = wave * 32 + c * 8;
        load16_lds(Arow + (size_t)(row8 + l8) * 256 + kb + gsw, &dst[row8 * 64]);
      }
    } else {
      const unsigned short* Arow = xnode + (size_t)rowBase * 512;
      int k0 = kb - 256;
#pragma unroll
      for (int c = 0; c < 4; ++c) {
        int row8 = wave * 32 + c * 8;
        load16_lds(Arow + (size_t)(row8 + l8) * 512 + k0 + gsw, &dst[row8 * 64]);
      }
    }
  };

  stageA(As[0], 0);
  STAGE(Bs[0], Brow, 768, 128, 0)
#pragma unroll
  for (int ti = 0; ti < 12; ++ti) {
    if (ti < 11) {
      stageA(As[(ti + 1) & 1], (ti + 1) * 64);
      STAGE(Bs[(ti + 1) & 1], Brow, 768, 128, (ti + 1) * 64)
      STEP_SYNC(8)
      if (ti == 10) {
#pragma unroll
        for (int i = 0; i < 4; ++i)
#pragma unroll
          for (int r2 = 0; r2 < 4; ++r2) {
            int r = rowBase + wm + i * 16 + q * 4 + r2;
            int b = r & 127;
            int node = base + v0 + (r >> 7);
            size_t o = (size_t)r * 256 + m;
            size_t co = ((size_t)(2 * node + 1) * 128 + b) * 256 + m;
            pfl[i][r2] = FHL[o];
            pfr[i][r2] = FHR[o];
            pc0[i][r2] = cbuf[co];
            pc1v[i][r2] = cbuf[co + 32768];
          }
      }
    } else {
      STEP_SYNC(63)
    }
    MFMA_BODY(As[ti & 1], Bs[ti & 1], 4, 64)
    __builtin_amdgcn_s_barrier();
  }

#pragma unroll
  for (int i = 0; i < 4; ++i)
#pragma unroll
    for (int r2 = 0; r2 < 4; ++r2) {
      int r = rowBase + wm + i * 16 + q * 4 + r2;
      int vloc = r >> 7, b = r & 127;
      int vg = v0 + vloc;
      int node = base + vg;
      float pf = acc[i][3][r2] + bf;
      float f0 = sigf(pf + pfl[i][r2]);
      float f1 = sigf(pf + pfr[i][r2]);
      float ii = sigf(acc[i][0][r2] + bi);
      float uu = tanh_a(acc[i][1][r2] + bu);
      float oo = sigf(acc[i][2][r2] + bo);
      float cc = ii * uu + f0 * pc0[i][r2] + f1 * pc1v[i][r2];
      float hh = oo * tanh_a(cc);
      if (lvl == 0) {
        out[b * 256 + m] = hh;
      } else {
        cbuf[((size_t)node * 128 + b) * 256 + m] = cc;
        int rowA = (vg & 1) * (n >> 1) * 128 + (vg >> 1) * 128 + b;
        Ain[(size_t)rowA * 320 + m] = f2bf(hh);
        if (m < 64)
          Ain[(size_t)rowA * 320 + 256 + m] = f2bf(rel[((size_t)b * NNODE + node) * 64 + m]);
      }
    }
}

// ---------------------------------------------------------------------------
// Leaf GEMM + epilogue, multi-row-tile (RT=4). Grid (8,64); block handles
// tiles ty = by*4 + r. Next tile's k=0 staged during the previous tile's
// last step; epilogue overlaps the staging latency.
__global__ __launch_bounds__(256, 2) void k_leaf(
    const unsigned short* __restrict__ xleaf, const unsigned short* __restrict__ Bt,
    float* __restrict__ cbuf, unsigned short* __restrict__ Ain,
    const float* __restrict__ rel,
    const float* __restrict__ bix, const float* __restrict__ bih,
    const float* __restrict__ bux, const float* __restrict__ buh,
    const float* __restrict__ box, const float* __restrict__ boh) {
  __shared__ alignas(16) unsigned short As[2][128 * 64];
  __shared__ alignas(16) unsigned short Bs[2][96 * 64];
  int bx, by; swz_blk(bx, by);
  LANE_SETUP
  const int RT = 4;
  const unsigned short* Brow = Bt + (size_t)bx * 96 * 512;
  const int m = (bx * 2 + wc) * 16 + m16;

  float bi = bix[m] + bih[m];
  float bu = bux[m] + buh[m];
  float bo = box[m] + boh[m];

  // Prologue: tile (by*RT), k=0.
  {
    const unsigned short* Arow = xleaf + (size_t)(by * RT) * 128 * 512;
    STAGE(As[0], Arow, 512, 128, 0)
#pragma unroll
    for (int c = 0; c < 3; ++c) {
      int row8 = wave * 24 + c * 8;
      load16_lds(Brow + (size_t)(row8 + l8) * 512 + 0 + gsw, &Bs[0][row8 * 64]);
    }
  }

  for (int r = 0; r < RT; ++r) {
    const int ty = by * RT + r;
    const unsigned short* Arow = xleaf + (size_t)ty * 128 * 512;
    const unsigned short* ArowN = xleaf + (size_t)(ty + 1) * 128 * 512;
    f32x4 acc[4][3] = {};
#pragma unroll
    for (int ti = 0; ti < 8; ++ti) {
      if (ti < 7) {
        int kn = (ti + 1) * 64;
        STAGE(As[(ti + 1) & 1], Arow, 512, 128, kn)
#pragma unroll
        for (int c = 0; c < 3; ++c) {
          int row8 = wave * 24 + c * 8;
          load16_lds(Brow + (size_t)(row8 + l8) * 512 + kn + gsw, &Bs[(ti + 1) & 1][row8 * 64]);
        }
        STEP_SYNC(7)
      } else if (r + 1 < RT) {
        // Next tile's k=0 into buf0; its latency hides under this epilogue.
        STAGE(As[0], ArowN, 512, 128, 0)
#pragma unroll
        for (int c = 0; c < 3; ++c) {
          int row8 = wave * 24 + c * 8;
          load16_lds(Brow + (size_t)(row8 + l8) * 512 + 0 + gsw, &Bs[0][row8 * 64]);
        }
        STEP_SYNC(7)
      } else {
        STEP_SYNC(0)
      }
      MFMA_BODY(As[ti & 1], Bs[ti & 1], 3, 48)
      __builtin_amdgcn_s_barrier();
    }

    // Epilogue for tile ty.
#pragma unroll
    for (int i = 0; i < 4; ++i)
#pragma unroll
      for (int r2 = 0; r2 < 4; ++r2) {
        int lr = wm + i * 16 + q * 4 + r2;
        int b = lr;
        int node = 255 + ty;
        float ii = sigf(acc[i][0][r2] + bi);
        float uu = tanh_a(acc[i][1][r2] + bu);
        float oo = sigf(acc[i][2][r2] + bo);
        float cc = ii * uu;
        float hh = oo * tanh_a(cc);
        cbuf[((size_t)node * 128 + b) * 256 + m] = cc;
        int rowA = (ty & 1) * 16384 + (ty >> 1) * 128 + b;
        Ain[(size_t)rowA * 320 + m] = f2bf(hh);
        if (m < 64)
          Ain[(size_t)rowA * 320 + 256 + m] = f2bf(rel[((size_t)b * NNODE + node) * 64 + m]);
      }
  }
}

// ---------------------------------------------------------------------------
// Fused tail: levels 4..0 in one launch, grid (8,16) = 128 blocks (all
// co-resident), grid barrier between the 15 GEMM phases.
__global__ __launch_bounds__(256, 2) void k_tail(
    unsigned short* __restrict__ Ain, const unsigned short* __restrict__ xbf,
    const unsigned short* __restrict__ WA2t, const unsigned short* __restrict__ WG2t,
    const unsigned short* __restrict__ WEX2t,
    unsigned short* __restrict__ h1, float* __restrict__ c1,
    float* __restrict__ FHL, float* __restrict__ FHR,
    unsigned short* __restrict__ HT, float* __restrict__ cbuf,
    const float* __restrict__ rel, float* __restrict__ out,
    const float* __restrict__ bsi, const float* __restrict__ bsh,
    const float* __restrict__ bix, const float* __restrict__ bih,
    const float* __restrict__ bux, const float* __restrict__ buh,
    const float* __restrict__ box, const float* __restrict__ boh,
    const float* __restrict__ bfx, const float* __restrict__ bfh,
    unsigned* __restrict__ bar) {
  __shared__ alignas(16) unsigned short As[2][128 * 64];
  __shared__ alignas(16) unsigned short Bs[2][160 * 64];
  const int bx = blockIdx.x, by = blockIdx.y;
  LANE_SETUP
  const int m = (bx * 2 + wc) * 16 + m16;

  for (int lvl = 4; lvl >= 0; --lvl) {
    const int n = 1 << lvl;
    const int base = n - 1;

    if (by < n) {  // ---- g1: A = AinL rows [by*128), K=320, B = WA2t ----
      const unsigned short* Arow = Ain + (size_t)by * 128 * 320;
      const unsigned short* Brow = WA2t + (size_t)bx * 160 * 320;
      float bi = bsi[m] + bsh[m];
      float bg = bsi[512 + m] + bsh[512 + m];
      float bo = bsi[768 + m] + bsh[768 + m];
      f32x4 acc[4][5] = {};
      STAGE(As[0], Arow, 320, 128, 0)
      STAGE(Bs[0], Brow, 320, 160, 0)
#pragma unroll
      for (int ti = 0; ti < 5; ++ti) {
        if (ti < 4) {
          STAGE(As[(ti + 1) & 1], Arow, 320, 128, (ti + 1) * 64)
          STAGE(Bs[(ti + 1) & 1], Brow, 320, 160, (ti + 1) * 64)
          STEP_SYNC(9)
        } else {
          STEP_SYNC(0)
        }
        MFMA_BODY(As[ti & 1], Bs[ti & 1], 5, 80)
        __builtin_amdgcn_s_barrier();
      }
#pragma unroll
      for (int i = 0; i < 4; ++i)
#pragma unroll
        for (int r2 = 0; r2 < 4; ++r2) {
          int r = by * 128 + wm + i * 16 + q * 4 + r2;
          float ii = sigf(acc[i][0][r2] + bi);
          float gg = tanh_a(acc[i][2][r2] + bg);
          float oo = sigf(acc[i][3][r2] + bo);
          float cv = ii * gg;
          size_t o = (size_t)r * 256 + m;
          h1[o] = f2bf(oo * tanh_a(cv));
          c1[o] = cv;
          FHL[o] = acc[i][4][r2];
        }
    }
    gridbar(bar, bar + 1);

    if (by < n) {  // ---- g2: A = [h1 | AinR], K=576, B = WG2t ----
      const unsigned short* Brow = WG2t + (size_t)bx * 160 * 576;
      float b0 = bsi[m] + bsh[m];
      float b1 = bsi[256 + m] + bsh[256 + m];
      float b2 = bsi[512 + m] + bsh[512 + m];
      float b3 = bsi[768 + m] + bsh[768 + m];
      f32x4 acc[4][5] = {};
      auto stA = [&](unsigned short* dst, int kb) {
        if (kb < 256) {
          const unsigned short* Arow = h1 + (size_t)by * 128 * 256;
#pragma unroll
          for (int c = 0; c < 4; ++c) {
            int row8 = wave * 32 + c * 8;
            load16_lds(Arow + (size_t)(row8 + l8) * 256 + kb + gsw, &dst[row8 * 64]);
          }
        } else {
          const unsigned short* Arow = Ain + (size_t)(n + by) * 128 * 320;
          int k0 = kb - 256;
#pragma unroll
          for (int c = 0; c < 4; ++c) {
            int row8 = wave * 32 + c * 8;
            load16_lds(Arow + (size_t)(row8 + l8) * 320 + k0 + gsw, &dst[row8 * 64]);
          }
        }
      };
      stA(As[0], 0);
      STAGE(Bs[0], Brow, 576, 160, 0)
#pragma unroll
      for (int ti = 0; ti < 9; ++ti) {
        if (ti < 8) {
          stA(As[(ti + 1) & 1], (ti + 1) * 64);
          STAGE(Bs[(ti + 1) & 1], Brow, 576, 160, (ti + 1) * 64)
          STEP_SYNC(9)
        } else {
          STEP_SYNC(0)
        }
        MFMA_BODY(As[ti & 1], Bs[ti & 1], 5, 80)
        __builtin_amdgcn_s_barrier();
      }
#pragma unroll
      for (int i = 0; i < 4; ++i)
#pragma unroll
        for (int r2 = 0; r2 < 4; ++r2) {
          int r = by * 128 + wm + i * 16 + q * 4 + r2;
          size_t o = (size_t)r * 256 + m;
          float ii = sigf(acc[i][0][r2] + b0);
          float ff = sigf(acc[i][1][r2] + b1);
          float gg = tanh_a(acc[i][2][r2] + b2);
          float oo = sigf(acc[i][3][r2] + b3);
          float c2 = ff * c1[o] + ii * gg;
          HT[o] = f2bf(oo * tanh_a(c2));
          FHR[o] = acc[i][4][r2];
        }
    }
    gridbar(bar, bar + 1);

    if (by < n) {  // ---- g3: A = [HT | xnode], K=768, B = WEX2t ----
      const unsigned short* xnode = xbf + (size_t)base * 128 * 512;
      const unsigned short* Brow = WEX2t + (size_t)bx * 128 * 768;
      float bi = bix[m] + bih[m];
      float bu = bux[m] + buh[m];
      float bo = box[m] + boh[m];
      float bf = bfx[m] + bfh[m];
      f32x4 acc[4][4] = {};
      auto stA = [&](unsigned short* dst, int kb) {
        if (kb < 256) {
          const unsigned short* Arow = HT + (size_t)by * 128 * 256;
#pragma unroll
          for (int c = 0; c < 4; ++c) {
            int row8 = wave * 32 + c * 8;
            load16_lds(Arow + (size_t)(row8 + l8) * 256 + kb + gsw, &dst[row8 * 64]);
          }
        } else {
          const unsigned short* Arow = xnode + (size_t)by * 128 * 512;
          int k0 = kb - 256;
#pragma unroll
          for (int c = 0; c < 4; ++c) {
            int row8 = wave * 32 + c * 8;
            load16_lds(Arow + (size_t)(row8 + l8) * 512 + k0 + gsw, &dst[row8 * 64]);
          }
        }
      };
      stA(As[0], 0);
      STAGE(Bs[0], Brow, 768, 128, 0)
#pragma unroll
      for (int ti = 0; ti < 12; ++ti) {
        if (ti < 11) {
          stA(As[(ti + 1) & 1], (ti + 1) * 64);
          STAGE(Bs[(ti + 1) & 1], Brow, 768, 128, (ti + 1) * 64)
          STEP_SYNC(8)
        } else {
          STEP_SYNC(0)
        }
        MFMA_BODY(As[ti & 1], Bs[ti & 1], 4, 64)
        __builtin_amdgcn_s_barrier();
      }
#pragma unroll
      for (int i = 0; i < 4; ++i)
#pragma unroll
        for (int r2 = 0; r2 < 4; ++r2) {
          int lr = wm + i * 16 + q * 4 + r2;
          int b = lr;
          int node = base + by;
          size_t o = (size_t)(by * 128 + lr) * 256 + m;
          size_t co = ((size_t)(2 * node + 1) * 128 + b) * 256 + m;
          float pf = acc[i][3][r2] + bf;
          float f0 = sigf(pf + FHL[o]);
          float f1 = sigf(pf + FHR[o]);
          float ii = sigf(acc[i][0][r2] + bi);
          float uu = tanh_a(acc[i][1][r2] + bu);
          float oo = sigf(acc[i][2][r2] + bo);
          float cc = ii * uu + f0 * cbuf[co] + f1 * cbuf[co + 32768];
          float hh = oo * tanh_a(cc);
          if (lvl == 0) {
            out[b * 256 + m] = hh;
          } else {
            cbuf[((size_t)node * 128 + b) * 256 + m] = cc;
            int rowA = (by & 1) * (n >> 1) * 128 + (by >> 1) * 128 + b;
            Ain[(size_t)rowA * 320 + m] = f2bf(hh);
            if (m < 64)
              Ain[(size_t)rowA * 320 + 256 + m] = f2bf(rel[((size_t)b * NNODE + node) * 64 + m]);
          }
        }
    }
    if (lvl > 0) gridbar(bar, bar + 1);
  }
}

// ---------------------------------------------------------------------------
extern "C" void kernel_launch(void* const* d_in, const int* in_sizes, int n_in,
                              void* d_out, int out_size, void* d_ws, size_t ws_size,
                              hipStream_t stream) {
  const float* wte = (const float*)d_in[0];
  const float* rel = (const float*)d_in[1];
  const float* Wix = (const float*)d_in[3];
  const float* bix = (const float*)d_in[4];
  const float* Wfx = (const float*)d_in[5];
  const float* bfx = (const float*)d_in[6];
  const float* Wux = (const float*)d_in[7];
  const float* bux = (const float*)d_in[8];
  const float* Wox = (const float*)d_in[9];
  const float* box = (const float*)d_in[10];
  const float* Wih = (const float*)d_in[11];
  const float* bih = (const float*)d_in[12];
  const float* Wfh = (const float*)d_in[13];
  const float* bfh = (const float*)d_in[14];
  const float* Wuh = (const float*)d_in[15];
  const float* buh = (const float*)d_in[16];
  const float* Woh = (const float*)d_in[17];
  const float* boh = (const float*)d_in[18];
  const float* Wsi = (const float*)d_in[19];
  const float* Wsh = (const float*)d_in[20];
  const float* bsi = (const float*)d_in[21];
  const float* bsh = (const float*)d_in[22];
  float* out = (float*)d_out;
  (void)in_sizes; (void)n_in; (void)out_size;

  int INT_MAXN;
  if (ws_size >= (size_t)310 * 1024 * 1024)      INT_MAXN = 128;
  else if (ws_size >= (size_t)200 * 1024 * 1024) INT_MAXN = 32;
  else                                           INT_MAXN = 8;
  const int crowsMax = INT_MAXN * 128;

  char* ws = (char*)d_ws;
  size_t off = 0;
  auto alloc = [&](size_t bytes) {
    size_t o = off; off += (bytes + 255) & ~(size_t)255; return o;
  };
  unsigned short* xbf  = (unsigned short*)(ws + alloc((size_t)NNODE * 128 * 512 * 2));
  float*          cbuf = (float*)         (ws + alloc((size_t)NNODE * 128 * 256 * 4));
  unsigned short* Ain  = (unsigned short*)(ws + alloc((size_t)32768 * 320 * 2));
  unsigned short* WL2t = (unsigned short*)(ws + alloc((size_t)768 * 512 * 2));
  unsigned short* WA2t = (unsigned short*)(ws + alloc((size_t)1280 * 320 * 2));
  unsigned short* WG2t = (unsigned short*)(ws + alloc((size_t)1280 * 576 * 2));
  unsigned short* WEX2t= (unsigned short*)(ws + alloc((size_t)1024 * 768 * 2));
  unsigned short* h1   = (unsigned short*)(ws + alloc((size_t)crowsMax * 256 * 2));
  float*          c1   = (float*)         (ws + alloc((size_t)crowsMax * 256 * 4));
  float*          FHL  = (float*)         (ws + alloc((size_t)crowsMax * 256 * 4));
  float*          FHR  = (float*)         (ws + alloc((size_t)crowsMax * 256 * 4));
  unsigned short* HT   = (unsigned short*)(ws + alloc((size_t)crowsMax * 256 * 2));
  unsigned*       bar  = (unsigned*)      (ws + alloc(256));

  k_prep_x<<<32704, 256, 0, stream>>>(wte, xbf, bar);
  k_prep_w<<<9088, 256, 0, stream>>>(Wix, Wux, Wox, Wfx, Wih, Wuh, Woh, Wfh,
                                     Wsi, Wsh, WL2t, WA2t, WG2t, WEX2t);

  // Leaves: fused GEMM over xbf rows [255*128, 511*128), 4 row-tiles/block.
  k_leaf<<<dim3(8, 64), 256, 0, stream>>>(xbf + (size_t)255 * 128 * 512, WL2t,
                                          cbuf, Ain, rel, bix, bih, bux, buh, box, boh);

  const bool fuse = (INT_MAXN >= 16);
  const int lvlMin = fuse ? 5 : 0;
  for (int lvl = 7; lvl >= lvlMin; --lvl) {
    int n = 1 << lvl;
    int base = n - 1;
    int cn = (n < INT_MAXN) ? n : INT_MAXN;
    for (int v0 = 0; v0 < n; v0 += cn) {
      const unsigned short* AinL = Ain + (size_t)(v0 * 128) * 320;
      const unsigned short* AinR = Ain + (size_t)((n + v0) * 128) * 320;
      const unsigned short* xnode = xbf + (size_t)(base + v0) * 128 * 512;
      k_gemm1<<<dim3(8, cn), 256, 0, stream>>>(AinL, WA2t, h1, c1, FHL, bsi, bsh);
      k_gemm2<<<dim3(8, cn), 256, 0, stream>>>(h1, AinR, WG2t, c1, HT, FHR, bsi, bsh);
      k_gemm3<<<dim3(8, cn), 256, 0, stream>>>(HT, xnode, WEX2t, FHL, FHR, cbuf, Ain,
                                               rel, out, bix, bih, bux, buh, box, boh,
                                               bfx, bfh, base, v0, n, lvl);
    }
  }
  if (fuse) {
    k_tail<<<dim3(8, 16), 256, 0, stream>>>(Ain, xbf, WA2t, WG2t, WEX2t,
                                            h1, c1, FHL, FHR, HT, cbuf, rel, out,
                                            bsi, bsh, bix, bih, bux, buh, box, boh,
                                            bfx, bfh, bar);
  }
}